// Round 1
// baseline (332.381 us; speedup 1.0000x reference)
//
#include <hip/hip_runtime.h>
#include <stdint.h>

typedef unsigned short u16;
typedef __bf16 bf16x8 __attribute__((ext_vector_type(8)));
typedef float f32x4 __attribute__((ext_vector_type(4)));

// Sizes
// x:  [16][256][64][64] fp32
// w:  [256][128][4][4]  fp32
// out:[16][128][128][128] fp32
// x_t (ws): [16][66][66][256] bf16, spatially padded by 1 with zeros
// Wk  (ws): [4 classes][128 co][k=tap*256+ci] bf16
static const size_t XT_BYTES = (size_t)16 * 66 * 66 * 256 * 2; // 35,684,352
static const size_t WK_BYTES = (size_t)4 * 128 * 1024 * 2;     //  1,048,576

__device__ __forceinline__ u16 f2bf(float f) {
  unsigned u = __float_as_uint(f);
  unsigned r = (u + 0x7fff + ((u >> 16) & 1)) >> 16; // RNE
  return (u16)r;
}

// async 16B global->LDS
__device__ __forceinline__ void ld_g2l16(const u16* g, void* l) {
  __builtin_amdgcn_global_load_lds(
      (const __attribute__((address_space(1))) unsigned int*)(uintptr_t)g,
      (__attribute__((address_space(3))) unsigned int*)(unsigned int)(uintptr_t)l,
      16, 0, 0);
}

// ---------------- prep: x fp32 NCHW -> bf16 padded NHWC ----------------
__global__ __launch_bounds__(256) void prep_x(const float* __restrict__ x,
                                              u16* __restrict__ xt) {
  __shared__ __align__(16) u16 sh[64 * 264]; // [iw][ci], pad 8 keeps 16B align
  const int t = threadIdx.x;
  const int ihp = blockIdx.x; // 0..65
  const int n = blockIdx.y;   // 0..15
  u16* xtn = xt + ((size_t)(n * 66 + ihp)) * 66 * 256;
  if (ihp == 0 || ihp == 65) {
    for (int j = 0; j < 9; ++j) {
      int idx = j * 256 + t;
      if (idx < 2112) ((uint4*)xtn)[idx] = make_uint4(0, 0, 0, 0);
    }
    return;
  }
  const int ih = ihp - 1;
  {
    const int iw = t & 63;
    const int cib = t >> 6; // 0..3
    for (int it = 0; it < 64; ++it) {
      int ci = it * 4 + cib;
      float v = x[(((size_t)n * 256 + ci) * 64 + ih) * 64 + iw];
      sh[iw * 264 + ci] = f2bf(v);
    }
  }
  __syncthreads();
  for (int j = 0; j < 8; ++j) {
    int idx = j * 256 + t;
    int iw = idx >> 5;    // 0..63
    int chunk = idx & 31; // 0..31
    uint4 v = *(const uint4*)&sh[iw * 264 + chunk * 8];
    *(uint4*)&xtn[(size_t)(iw + 1) * 256 + chunk * 8] = v;
  }
  if (t < 64) { // side borders iwp = 0, 65
    int iwp = (t >> 5) * 65;
    int chunk = t & 31;
    *(uint4*)&xtn[(size_t)iwp * 256 + chunk * 8] = make_uint4(0, 0, 0, 0);
  }
}

// ---------------- prep: weights -> per-class k-contiguous bf16 ----------------
__global__ __launch_bounds__(256) void prep_w(const float* __restrict__ w,
                                              u16* __restrict__ wk) {
  int id = blockIdx.x * 256 + threadIdx.x; // < 524288
  int ci = id & 255;
  int tap = (id >> 8) & 3;
  int co = (id >> 10) & 127;
  int cls = id >> 17; // 0..3
  int p = cls >> 1, q = cls & 1;
  int dh = tap >> 1, dw = tap & 1;
  int kh = 2 * dh + 1 - p;
  int kw = 2 * dw + 1 - q;
  wk[id] = f2bf(w[((ci * 128 + co) * 4 + kh) * 4 + kw]);
}

// ---------------- main: per-parity-class implicit GEMM ----------------
// C[co][col] = sum_k Wk[cls][co][k] * B[k][col],  k=tap*256+ci,
// col = mrow*64 + l (2 m-rows per block), per class (p,q):
//   ih = m+p-dh, iw = l+q-dw  (handled via padded x_t: ihp=ih+1, iwp=iw+1)
__global__ __launch_bounds__(256) void gemm_ct(const u16* __restrict__ xt,
                                               const u16* __restrict__ wk,
                                               const float* __restrict__ bias,
                                               float* __restrict__ out) {
  __shared__ uint4 Ash[512]; // [co 0..127][slot 0..3], slot holds chunk slot^(co&3)
  __shared__ uint4 Bsh[512]; // [col 0..127][slot 0..3]
  const int t = threadIdx.x;
  const int lane = t & 63;
  const int wv = t >> 6;
  const int wm = wv >> 1, wn = wv & 1;
  const int quad = lane >> 4, l15 = lane & 15;
  const int mt = blockIdx.x;  // 0..31
  const int n = blockIdx.y;   // 0..15
  const int cls = blockIdx.z; // 0..3
  const int p = cls >> 1, q = cls & 1;
  const int m0 = mt * 2;

  // staging decomposition (row = idx>>2 is co or col; slot = idx&3)
  const int idx0 = t, idx1 = 256 + t;
  const int ro0 = idx0 >> 2, sl0 = idx0 & 3, ch0 = sl0 ^ (ro0 & 3);
  const int ro1 = idx1 >> 2, sl1 = idx1 & 3, ch1 = sl1 ^ (ro1 & 3);
  const u16* wkc = wk + (size_t)cls * 128 * 1024;

  // constant frag-read offsets (uint4 index), XOR-swizzled
  int aoff[4], boff[4];
#pragma unroll
  for (int i = 0; i < 4; ++i) {
    int co = wm * 64 + i * 16 + l15;
    aoff[i] = co * 4 + (quad ^ (co & 3));
    int col = wn * 64 + i * 16 + l15;
    boff[i] = col * 4 + (quad ^ (col & 3));
  }

  f32x4 acc[4][4];
#pragma unroll
  for (int i = 0; i < 4; ++i)
#pragma unroll
    for (int j = 0; j < 4; ++j) acc[i][j] = (f32x4){0.f, 0.f, 0.f, 0.f};

  const int mr0 = ro0 >> 6, lB0 = ro0 & 63;
  const int mr1 = ro1 >> 6, lB1 = ro1 & 63;

  for (int tap = 0; tap < 4; ++tap) {
    const int dh = tap >> 1, dw = tap & 1;
    const u16* pA0 = wkc + ro0 * 1024 + tap * 256 + ch0 * 8;
    const u16* pA1 = wkc + ro1 * 1024 + tap * 256 + ch1 * 8;
    const int ihp0 = m0 + mr0 + p - dh + 1;
    const int iwp0 = lB0 + q - dw + 1;
    const int ihp1 = m0 + mr1 + p - dh + 1;
    const int iwp1 = lB1 + q - dw + 1;
    const u16* pB0 = xt + (((size_t)n * 66 + ihp0) * 66 + iwp0) * 256 + ch0 * 8;
    const u16* pB1 = xt + (((size_t)n * 66 + ihp1) * 66 + iwp1) * 256 + ch1 * 8;
#pragma unroll
    for (int s = 0; s < 8; ++s) {
      __syncthreads(); // previous compute done reading LDS
      ld_g2l16(pA0 + s * 32, &Ash[idx0]);
      ld_g2l16(pA1 + s * 32, &Ash[idx1]);
      ld_g2l16(pB0 + s * 32, &Bsh[idx0]);
      ld_g2l16(pB1 + s * 32, &Bsh[idx1]);
      __syncthreads(); // implicit vmcnt(0): loads landed
      bf16x8 af[4], bfr[4];
#pragma unroll
      for (int i = 0; i < 4; ++i) af[i] = *(const bf16x8*)&Ash[aoff[i]];
#pragma unroll
      for (int i = 0; i < 4; ++i) bfr[i] = *(const bf16x8*)&Bsh[boff[i]];
#pragma unroll
      for (int i = 0; i < 4; ++i)
#pragma unroll
        for (int j = 0; j < 4; ++j)
          acc[i][j] = __builtin_amdgcn_mfma_f32_16x16x32_bf16(af[i], bfr[j],
                                                              acc[i][j], 0, 0, 0);
    }
  }

  // epilogue: C/D layout col=lane&15, row=quad*4+reg
  const int oh = 2 * (m0 + wn) + p;
#pragma unroll
  for (int i = 0; i < 4; ++i) {
#pragma unroll
    for (int j = 0; j < 4; ++j) {
      f32x4 v = acc[i][j];
      int l = j * 16 + l15;
      int ow = 2 * l + q;
#pragma unroll
      for (int r = 0; r < 4; ++r) {
        int co = wm * 64 + i * 16 + quad * 4 + r;
        out[(((size_t)n * 128 + co) * 128 + oh) * 128 + ow] = v[r] + bias[co];
      }
    }
  }
}

// ---------------- safety fallback (ws too small): direct fp32 ----------------
__global__ __launch_bounds__(256) void ct_fallback(const float* __restrict__ x,
                                                   const float* __restrict__ w,
                                                   const float* __restrict__ bias,
                                                   float* __restrict__ out) {
  size_t id = (size_t)blockIdx.x * 256 + threadIdx.x;
  if (id >= (size_t)16 * 128 * 128 * 128) return;
  int ow = (int)(id & 127), oh = (int)(id >> 7) & 127;
  int co = (int)(id >> 14) & 127, n = (int)(id >> 21);
  int pp = oh & 1, m = oh >> 1, qq = ow & 1, l = ow >> 1;
  float s = bias[co];
  for (int ci = 0; ci < 256; ++ci) {
    for (int dh = 0; dh < 2; ++dh) {
      int ih = m + pp - dh;
      if (ih < 0 || ih > 63) continue;
      int kh = 2 * dh + 1 - pp;
      for (int dw = 0; dw < 2; ++dw) {
        int iw = l + qq - dw;
        if (iw < 0 || iw > 63) continue;
        int kw = 2 * dw + 1 - qq;
        s += x[(((size_t)n * 256 + ci) * 64 + ih) * 64 + iw] *
             w[((ci * 128 + co) * 4 + kh) * 4 + kw];
      }
    }
  }
  out[id] = s;
}

extern "C" void kernel_launch(void* const* d_in, const int* in_sizes, int n_in,
                              void* d_out, int out_size, void* d_ws, size_t ws_size,
                              hipStream_t stream) {
  const float* x = (const float*)d_in[0];
  const float* w = (const float*)d_in[1];
  const float* bias = (const float*)d_in[2];
  float* out = (float*)d_out;
  if (ws_size >= XT_BYTES + WK_BYTES) {
    u16* xt = (u16*)d_ws;
    u16* wk = (u16*)((char*)d_ws + XT_BYTES);
    hipLaunchKernelGGL(prep_x, dim3(66, 16), dim3(256), 0, stream, x, xt);
    hipLaunchKernelGGL(prep_w, dim3(2048), dim3(256), 0, stream, w, wk);
    hipLaunchKernelGGL(gemm_ct, dim3(32, 16, 4), dim3(256), 0, stream, xt, wk, bias, out);
  } else {
    hipLaunchKernelGGL(ct_fallback, dim3(131072), dim3(256), 0, stream, x, w, bias, out);
  }
}